// Round 1
// baseline (1072.211 us; speedup 1.0000x reference)
//
#include <hip/hip_runtime.h>

// Frequency-domain room simulation.
// Reference per block b:
//   sf += env_b; spec = rfft(sf,ortho); sf = irfft(res_b*spec,ortho);
//   mic_b = sf[8,8,8]; sf = box3x3x3(sf)
// FFT (time axis) commutes with box-sum (spatial axis), so keep SF = FFT(sf)
// (unnormalized DFT convention):
//   T  = clip(res_b,0,1) * (SF + FFT(env_b))
//   mic_b = (1/1024) * IDFT(T[mic_cell])
//   SF = box3x3x3(T)     (complex, per frequency bin)

#define NCELLS 4096     // 16*16*16
#define NF     513      // 1024/2+1
#define NFFT   1024
#define MIC_CELL 2184   // 8*256 + 8*16 + 8

__device__ float2 g_SF[NCELLS * NF];   // field in freq domain (post-box)
__device__ float2 g_T [NCELLS * NF];   // pre-box spectrum for current block

// One workgroup per cell, 512 threads. Computes env_b -> forward FFT (DIF,
// natural in -> bitrev out) -> multiply by clipped res + add SF -> store T.
// Mic cell additionally runs inverse DIT (bitrev in -> natural out) and
// writes 1024 mic samples.
__global__ __launch_bounds__(512) void k_block(
    const float* __restrict__ tf,      // (16, 4096, 513)
    const float* __restrict__ imp,     // (16, 4096, 16)
    const float* __restrict__ noise,   // (16, 4096, 1024)
    float* __restrict__ out,           // (16384,)
    int b)
{
    __shared__ float re[NFFT];
    __shared__ float im[NFFT];
    __shared__ float2 W[NFFT / 2];     // W[i] = exp(-2*pi*i*i/1024)

    const int tid  = threadIdx.x;
    const int cell = blockIdx.x;

    // twiddle table (one sincos per thread, reused for all 20 stages)
    {
        float s, c;
        __sincosf(-6.28318530717958647692f * (float)tid * (1.0f / 1024.0f), &s, &c);
        W[tid] = make_float2(c, s);
    }

    // --- env = clip(linear_interp(impulses,1024),0,1) * noise ---
    const float* ip  = imp   + ((size_t)b * NCELLS + cell) * 16;
    const float* nzp = noise + ((size_t)b * NCELLS + cell) * (size_t)NFFT;
    for (int p = tid; p < NFFT; p += 512) {
        float coord = (p + 0.5f) * (16.0f / 1024.0f) - 0.5f;
        coord = fminf(fmaxf(coord, 0.0f), 15.0f);
        int lo = (int)coord;                 // floor (coord >= 0)
        int hi = lo + 1; if (hi > 15) hi = 15;
        float w = coord - (float)lo;
        float e = ip[lo] * (1.0f - w) + ip[hi] * w;
        e = fminf(fmaxf(e, 0.0f), 1.0f) * nzp[p];
        re[p] = e;
        im[p] = 0.0f;
    }
    __syncthreads();

    // --- forward FFT: radix-2 DIF, natural input -> bit-reversed output ---
    for (int lg = 9; lg >= 0; --lg) {
        const int len = 1 << lg;
        const int j  = tid & (len - 1);
        const int i0 = ((tid >> lg) << (lg + 1)) + j;
        const int i1 = i0 + len;
        float ar = re[i0], ai = im[i0];
        float br = re[i1], bi = im[i1];
        re[i0] = ar + br;  im[i0] = ai + bi;
        float dr = ar - br, di = ai - bi;
        float2 w = W[j << (9 - lg)];         // exp(-2*pi*i*j/(2*len))
        re[i1] = dr * w.x - di * w.y;
        im[i1] = dr * w.y + di * w.x;
        __syncthreads();
    }

    // --- T = clip(res,0,1) * (SF + E), stored as 513-bin half spectrum ---
    const float*  rp  = tf + ((size_t)b * NCELLS + cell) * NF;
    const float2* sfc = g_SF + (size_t)cell * NF;
    float2*       tc  = g_T  + (size_t)cell * NF;
    for (int p = tid; p < NFFT; p += 512) {
        int k  = __brev(p) >> 22;            // bit-reversed 10-bit index
        int kk = (k <= 512) ? k : (1024 - k);
        float r = fminf(fmaxf(rp[kk], 0.0f), 1.0f);
        float sr = 0.0f, si = 0.0f;
        if (b > 0) {
            float2 s0 = sfc[kk];
            sr = s0.x;
            si = (k <= 512) ? s0.y : -s0.y;  // conj for mirrored bins
        }
        float tr = r * (sr + re[p]);
        float ti = r * (si + im[p]);
        if (k <= 512) tc[k] = make_float2(tr, ti);
        re[p] = tr;                          // keep full spectrum for mic path
        im[p] = ti;
    }

    if (cell == MIC_CELL) {
        __syncthreads();
        // --- inverse FFT: radix-2 DIT, bit-reversed input -> natural output ---
        for (int lg = 0; lg <= 9; ++lg) {
            const int len = 1 << lg;
            const int j  = tid & (len - 1);
            const int i0 = ((tid >> lg) << (lg + 1)) + j;
            const int i1 = i0 + len;
            float2 w = W[j << (9 - lg)];     // conj -> exp(+2*pi*i*j/(2*len))
            float br = re[i1], bi = im[i1];
            float tr = br * w.x + bi * w.y;  // b * conj(w)
            float ti = bi * w.x - br * w.y;
            float ar = re[i0], ai = im[i0];
            re[i0] = ar + tr;  im[i0] = ai + ti;
            re[i1] = ar - tr;  im[i1] = ai - ti;
            __syncthreads();
        }
        for (int p = tid; p < NFFT; p += 512) {
            out[(size_t)b * NFFT + p] = re[p] * (1.0f / 1024.0f);
        }
    }
}

// SF[cell] = sum of T over 3x3x3 spatial neighborhood (zero padding).
__global__ __launch_bounds__(256) void k_box(int dummy)
{
    const int cell = blockIdx.x;
    const int x = cell >> 8, y = (cell >> 4) & 15, z = cell & 15;
    for (int f = threadIdx.x; f < NF; f += 256) {
        float sr = 0.0f, si = 0.0f;
        for (int dx = -1; dx <= 1; ++dx) {
            int nx = x + dx; if ((unsigned)nx > 15u) continue;
            for (int dy = -1; dy <= 1; ++dy) {
                int ny = y + dy; if ((unsigned)ny > 15u) continue;
                for (int dz = -1; dz <= 1; ++dz) {
                    int nz = z + dz; if ((unsigned)nz > 15u) continue;
                    int nc = (nx << 8) | (ny << 4) | nz;
                    float2 v = g_T[(size_t)nc * NF + f];
                    sr += v.x; si += v.y;
                }
            }
        }
        g_SF[(size_t)cell * NF + f] = make_float2(sr, si);
    }
    (void)dummy;
}

extern "C" void kernel_launch(void* const* d_in, const int* in_sizes, int n_in,
                              void* d_out, int out_size, void* d_ws, size_t ws_size,
                              hipStream_t stream)
{
    // setup_inputs order: x (unused), transfer_functions, impulses, noise
    const float* tf    = (const float*)d_in[1];
    const float* imp   = (const float*)d_in[2];
    const float* noise = (const float*)d_in[3];
    float* out = (float*)d_out;

    for (int b = 0; b < 16; ++b) {
        k_block<<<NCELLS, 512, 0, stream>>>(tf, imp, noise, out, b);
        if (b < 15) k_box<<<NCELLS, 256, 0, stream>>>(0);
    }
}

// Round 2
// 765.620 us; speedup vs baseline: 1.4004x; 1.4004x over previous
//
#include <hip/hip_runtime.h>

// Frequency-domain room simulation (see round-0 derivation).
// This round: spectra are stored FULL-LENGTH (1024 bins) in BIT-REVERSED bin
// order. The spatial box-sum is pointwise per bin, so the permutation is
// harmless, and every global access to g_T / g_SF becomes coalesced. The
// conjugate-symmetric half is stored redundantly (exactly preserved by the
// linear pipeline). Only the 513-entry tf row needs a bitrev gather, done
// from a padded LDS copy.
//
//   T  = clip(res_b,0,1) * (SF + FFT(env_b))     (bitrev bin order)
//   mic_b = (1/1024) * IDFT(T[mic_cell])         (DIT, bitrev->natural)
//   SF = box3x3x3(T)                             (complex, per bin)

#define NCELLS 4096     // 16*16*16
#define NFFT   1024
#define NF     513
#define MIC_CELL 2184   // 8*256 + 8*16 + 8

__device__ float2 g_SF[NCELLS * NFFT];   // field in freq domain (post-box)
__device__ float2 g_T [NCELLS * NFFT];   // pre-box spectrum for current block

__device__ __forceinline__ int pad32(int i) { return i + (i >> 5); }
__device__ __forceinline__ int pad16(int i) { return i + (i >> 4); }

// One WG (256 thr) per cell: env -> fused-radix FFT (5 LDS passes) ->
// T = res*(SF+E) -> store; mic cell also runs inverse DIT + writes output.
__global__ __launch_bounds__(256) void k_block(
    const float* __restrict__ tf,      // (16, 4096, 513)
    const float* __restrict__ imp,     // (16, 4096, 16)
    const float* __restrict__ noise,   // (16, 4096, 1024)
    float* __restrict__ out,           // (16384,)
    int b)
{
    __shared__ float re[1056], im[1056];       // padded: i + (i>>5)
    __shared__ float wr[544], wi[544];         // padded: i + (i>>4); W^i, i<512
    __shared__ float resl[546];                // padded clipped tf row

    const int tid  = threadIdx.x;
    const int cell = blockIdx.x;

    // twiddle table W[i] = exp(-2*pi*i*i/1024)
    for (int i = tid; i < 512; i += 256) {
        float s, c;
        __sincosf(-6.28318530717958647692f * (1.0f / 1024.0f) * (float)i, &s, &c);
        wr[pad16(i)] = c;  wi[pad16(i)] = s;
    }
    // clipped res row -> LDS
    const float* rp = tf + ((size_t)b * NCELLS + cell) * NF;
    for (int i = tid; i < NF; i += 256)
        resl[pad16(i)] = fminf(fmaxf(rp[i], 0.0f), 1.0f);

    // env = clip(linear_interp(impulses,1024),0,1) * noise
    const float* ip  = imp   + ((size_t)b * NCELLS + cell) * 16;
    const float* nzp = noise + ((size_t)b * NCELLS + cell) * (size_t)NFFT;
    #pragma unroll
    for (int it = 0; it < 4; ++it) {
        int p = tid + it * 256;
        float coord = (p + 0.5f) * (16.0f / 1024.0f) - 0.5f;
        coord = fminf(fmaxf(coord, 0.0f), 15.0f);
        int lo = (int)coord;
        int hi = lo + 1; if (hi > 15) hi = 15;
        float w = coord - (float)lo;
        float e = ip[lo] * (1.0f - w) + ip[hi] * w;
        e = fminf(fmaxf(e, 0.0f), 1.0f) * nzp[p];
        re[pad32(p)] = e;
        im[pad32(p)] = 0.0f;
    }
    __syncthreads();

    // forward FFT: 10 radix-2 DIF stages fused 2-at-a-time (5 LDS passes).
    // Thread owns points {base, base+LL, base+2LL, base+3LL}.
    #pragma unroll
    for (int lgU = 9; lgU >= 1; lgU -= 2) {
        const int lgL = lgU - 1;
        const int LL  = 1 << lgL;
        const int j   = tid & (LL - 1);
        const int g   = tid >> lgL;
        const int base = (g << (lgL + 2)) + j;
        const int p0 = pad32(base);
        const int p1 = pad32(base + LL);
        const int p2 = pad32(base + 2 * LL);
        const int p3 = pad32(base + 3 * LL);

        float a0r = re[p0], a0i = im[p0];
        float a1r = re[p1], a1i = im[p1];
        float a2r = re[p2], a2i = im[p2];
        float a3r = re[p3], a3i = im[p3];

        const int iu0 = j << (9 - lgU);
        const int iu1 = (j + LL) << (9 - lgU);
        const int il  = j << (9 - lgL);
        const float wu0r = wr[pad16(iu0)], wu0i = wi[pad16(iu0)];
        const float wu1r = wr[pad16(iu1)], wu1i = wi[pad16(iu1)];
        const float wlr  = wr[pad16(il)],  wli  = wi[pad16(il)];

        // stage U (len = 2*LL): pairs (p0,p2), (p1,p3)
        float u0r = a0r + a2r, u0i = a0i + a2i;
        float d0r = a0r - a2r, d0i = a0i - a2i;
        float u2r = d0r * wu0r - d0i * wu0i, u2i = d0r * wu0i + d0i * wu0r;
        float u1r = a1r + a3r, u1i = a1i + a3i;
        float d1r = a1r - a3r, d1i = a1i - a3i;
        float u3r = d1r * wu1r - d1i * wu1i, u3i = d1r * wu1i + d1i * wu1r;
        // stage L (len = LL): pairs (p0,p1), (p2,p3), same twiddle
        float e0r = u0r - u1r, e0i = u0i - u1i;
        float e1r = u2r - u3r, e1i = u2i - u3i;
        re[p0] = u0r + u1r;               im[p0] = u0i + u1i;
        re[p1] = e0r * wlr - e0i * wli;   im[p1] = e0r * wli + e0i * wlr;
        re[p2] = u2r + u3r;               im[p2] = u2i + u3i;
        re[p3] = e1r * wlr - e1i * wli;   im[p3] = e1r * wli + e1i * wlr;
        __syncthreads();
    }

    // T = res * (SF + E), all in bitrev bin order, fully coalesced
    const float2* sfc = g_SF + (size_t)cell * NFFT;
    float2*       tc  = g_T  + (size_t)cell * NFFT;
    #pragma unroll
    for (int it = 0; it < 4; ++it) {
        int p = tid + it * 256;
        int k = __brev(p) >> 22;                 // natural bin of slot p
        int kk = (k <= 512) ? k : (1024 - k);
        float r = resl[pad16(kk)];
        float sr = 0.0f, si = 0.0f;
        if (b > 0) { float2 s0 = sfc[p]; sr = s0.x; si = s0.y; }
        float tr = r * (sr + re[pad32(p)]);
        float ti = r * (si + im[pad32(p)]);
        tc[p] = make_float2(tr, ti);
        re[pad32(p)] = tr;
        im[pad32(p)] = ti;
    }

    if (cell == MIC_CELL) {
        __syncthreads();
        // inverse FFT: radix-2 DIT, bitrev input -> natural output
        for (int lg = 0; lg <= 9; ++lg) {
            const int len = 1 << lg;
            #pragma unroll
            for (int pr = tid; pr < 512; pr += 256) {
                const int jj = pr & (len - 1);
                const int i0 = ((pr >> lg) << (lg + 1)) + jj;
                const int i1 = i0 + len;
                const int iw = jj << (9 - lg);
                const float wR = wr[pad16(iw)], wI = wi[pad16(iw)];
                const int q0 = pad32(i0), q1 = pad32(i1);
                float brr = re[q1], bii = im[q1];
                float trr = brr * wR + bii * wI;   // b * conj(W)
                float tii = bii * wR - brr * wI;
                float arr = re[q0], aii = im[q0];
                re[q0] = arr + trr;  im[q0] = aii + tii;
                re[q1] = arr - trr;  im[q1] = aii - tii;
            }
            __syncthreads();
        }
        #pragma unroll
        for (int it = 0; it < 4; ++it) {
            int p = tid + it * 256;
            out[(size_t)b * NFFT + p] = re[pad32(p)] * (1.0f / 1024.0f);
        }
    }
}

// Separable tiled box-sum: WG = 4x4 (x,y)-tile x 8-bin chunk, all 16 z.
// Halo 6x6 rows loaded once (2.25 reads/cell), z-sum then 9-pt xy-sum in LDS.
__global__ __launch_bounds__(512) void k_box()
{
    __shared__ float2 Tt[576 * 8];   // 6x6 halo x 16 z x 8 bins
    __shared__ float2 Sz[576 * 8];   // after z-direction 3-sum

    const int tid  = threadIdx.x;
    const int tile = blockIdx.x & 15;
    const int f0   = (blockIdx.x >> 4) << 3;
    const int tx   = (tile >> 2) << 2;
    const int ty   = (tile & 3) << 2;

    for (int idx = tid; idx < 4608; idx += 512) {
        int fi = idx & 7, lc = idx >> 3;
        int hc = lc >> 4, z = lc & 15;
        int hx = hc / 6, hy = hc - hx * 6;
        int x = tx - 1 + hx, y = ty - 1 + hy;
        float2 v = make_float2(0.0f, 0.0f);
        if ((unsigned)x < 16u && (unsigned)y < 16u)
            v = g_T[(size_t)((x << 8) | (y << 4) | z) * NFFT + f0 + fi];
        Tt[idx] = v;
    }
    __syncthreads();

    for (int idx = tid; idx < 4608; idx += 512) {
        int z = (idx >> 3) & 15;
        float2 v = Tt[idx];
        if (z > 0)  { float2 u = Tt[idx - 8]; v.x += u.x; v.y += u.y; }
        if (z < 15) { float2 u = Tt[idx + 8]; v.x += u.x; v.y += u.y; }
        Sz[idx] = v;
    }
    __syncthreads();

    #pragma unroll
    for (int it = 0; it < 4; ++it) {
        int idx = tid + it * 512;
        int fi = idx & 7, oc = idx >> 3;
        int ox = oc >> 6, oy = (oc >> 4) & 3, z = oc & 15;
        float sr = 0.0f, si = 0.0f;
        #pragma unroll
        for (int dx = 0; dx < 3; ++dx)
            #pragma unroll
            for (int dy = 0; dy < 3; ++dy) {
                int hc = (ox + dx) * 6 + (oy + dy);
                float2 u = Sz[(hc * 16 + z) * 8 + fi];
                sr += u.x; si += u.y;
            }
        g_SF[(size_t)(((tx + ox) << 8) | ((ty + oy) << 4) | z) * NFFT + f0 + fi]
            = make_float2(sr, si);
    }
}

extern "C" void kernel_launch(void* const* d_in, const int* in_sizes, int n_in,
                              void* d_out, int out_size, void* d_ws, size_t ws_size,
                              hipStream_t stream)
{
    // setup_inputs order: x (unused), transfer_functions, impulses, noise
    const float* tf    = (const float*)d_in[1];
    const float* imp   = (const float*)d_in[2];
    const float* noise = (const float*)d_in[3];
    float* out = (float*)d_out;

    for (int b = 0; b < 16; ++b) {
        k_block<<<NCELLS, 256, 0, stream>>>(tf, imp, noise, out, b);
        if (b < 15) k_box<<<2048, 512, 0, stream>>>();
    }
}

// Round 3
// 432.317 us; speedup vs baseline: 2.4801x; 1.7710x over previous
//
#include <hip/hip_runtime.h>

// Frequency-domain room sim, 3-kernel phase split.
//   SF = DFT(sound_field) per cell (unnormalized); per block b:
//     T = clip(res,0,1) * (SF + DFT(env_b));  mic_b = IDFT(T[mic])/1024;
//     SF = box3x3x3(T)   (pointwise per bin -> recursion independent per bin)
// P1: all 16x4096 env FFTs + transpose to (b,bin,cell) fp16; tf clip+pack.
// P2: one WG per bin (513); 16-block recursion fully in registers
//     (z-column per thread), box via reg z-sum + LDS y/x exchanges.
// P3: 16 inverse FFTs of the mic spectra.

#define NFFT   1024
#define NF     513
#define NKP    257      // packed tf bin-pairs
#define NCELLS 4096
#define MICQ   136      // x*16+y = 8*16+8
#define PI2    6.28318530717958647692f

__device__ __forceinline__ int pd(int i) { return i + (i >> 5); }
__device__ __forceinline__ float clip01(float v) { return fminf(fmaxf(v, 0.0f), 1.0f); }
__device__ __forceinline__ unsigned pkh2(float a, float b) {
    union { _Float16 h[2]; unsigned u; } z;
    z.h[0] = (_Float16)a; z.h[1] = (_Float16)b;
    return z.u;
}
__device__ __forceinline__ unsigned cmp4(const uint4& v, int c) {
    return c == 0 ? v.x : c == 1 ? v.y : c == 2 ? v.z : v.w;
}

// ---------------- P1 ----------------
// WG = (block b, 16 cells). 256 threads.
__global__ __launch_bounds__(256) void k_p1(
    const float* __restrict__ tf, const float* __restrict__ imp,
    const float* __restrict__ noise, unsigned* __restrict__ Et,
    unsigned* __restrict__ TFt)
{
    __shared__ float2 FD[1056];              // padded 1024-pt complex buffer
    __shared__ unsigned ob[513 * 17 + 4];    // transpose buffer (17 = 16 cells + pad)

    const int tid = threadIdx.x;
    const int b   = blockIdx.x >> 8;
    const int c0  = (blockIdx.x & 255) << 4;

    // hoisted per-thread twiddles for the 5 fused DIF passes
    float2 tu0[5], tu1[5], tl[5];
    #pragma unroll
    for (int p = 0; p < 5; ++p) {
        const int lgU = 9 - 2 * p, lgL = lgU - 1, LL = 1 << lgL;
        const int j = tid & (LL - 1);
        const int iu0 = j << (9 - lgU), iu1 = (j + LL) << (9 - lgU), il = j << (9 - lgL);
        float s, c;
        __sincosf(-PI2 * (1.0f / 1024.0f) * (float)iu0, &s, &c); tu0[p] = make_float2(c, s);
        __sincosf(-PI2 * (1.0f / 1024.0f) * (float)iu1, &s, &c); tu1[p] = make_float2(c, s);
        __sincosf(-PI2 * (1.0f / 1024.0f) * (float)il,  &s, &c); tl[p]  = make_float2(c, s);
    }

    // noise prefetch double-buffer (4 coalesced floats/thread per cell)
    float nzA[4], nzB[4];
    {
        const float* np = noise + ((size_t)b * NCELLS + c0) * NFFT + tid;
        nzA[0] = np[0]; nzA[1] = np[256]; nzA[2] = np[512]; nzA[3] = np[768];
    }

    for (int cl = 0; cl < 16; ++cl) {
        if (cl < 15) {
            const float* np = noise + ((size_t)b * NCELLS + c0 + cl + 1) * NFFT + tid;
            nzB[0] = np[0]; nzB[1] = np[256]; nzB[2] = np[512]; nzB[3] = np[768];
        }
        const float* ip = imp + ((size_t)b * NCELLS + c0 + cl) * 16;

        // env = clip(linear_interp(imp,1024),0,1) * noise
        #pragma unroll
        for (int it = 0; it < 4; ++it) {
            int p = tid + it * 256;
            float coord = (p + 0.5f) * (16.0f / 1024.0f) - 0.5f;
            coord = fminf(fmaxf(coord, 0.0f), 15.0f);
            int lo = (int)coord;
            int hi = lo + 1 > 15 ? 15 : lo + 1;
            float w = coord - (float)lo;
            float e = ip[lo] * (1.0f - w) + ip[hi] * w;
            e = clip01(e) * nzA[it];
            FD[pd(p)] = make_float2(e, 0.0f);
        }
        __syncthreads();

        // forward FFT: 10 radix-2 DIF stages, fused 2/pass (5 passes)
        #pragma unroll
        for (int p = 0; p < 5; ++p) {
            const int lgU = 9 - 2 * p, lgL = lgU - 1, LL = 1 << lgL;
            const int j = tid & (LL - 1), g = tid >> lgL;
            const int base = (g << (lgL + 2)) + j;
            float2 a0 = FD[pd(base)], a1 = FD[pd(base + LL)];
            float2 a2 = FD[pd(base + 2 * LL)], a3 = FD[pd(base + 3 * LL)];
            float2 w0 = tu0[p], w1 = tu1[p], wl = tl[p];
            float u0r = a0.x + a2.x, u0i = a0.y + a2.y;
            float d0r = a0.x - a2.x, d0i = a0.y - a2.y;
            float u2r = d0r * w0.x - d0i * w0.y, u2i = d0r * w0.y + d0i * w0.x;
            float u1r = a1.x + a3.x, u1i = a1.y + a3.y;
            float d1r = a1.x - a3.x, d1i = a1.y - a3.y;
            float u3r = d1r * w1.x - d1i * w1.y, u3i = d1r * w1.y + d1i * w1.x;
            float e0r = u0r - u1r, e0i = u0i - u1i;
            float e1r = u2r - u3r, e1i = u2i - u3i;
            FD[pd(base)]          = make_float2(u0r + u1r, u0i + u1i);
            FD[pd(base + LL)]     = make_float2(e0r * wl.x - e0i * wl.y, e0r * wl.y + e0i * wl.x);
            FD[pd(base + 2 * LL)] = make_float2(u2r + u3r, u2i + u3i);
            FD[pd(base + 3 * LL)] = make_float2(e1r * wl.x - e1i * wl.y, e1r * wl.y + e1i * wl.x);
            __syncthreads();
        }

        // extract natural bins 0..512 (slot = bitrev) -> fp16 pack -> ob[:,cl]
        #pragma unroll
        for (int it = 0; it < 3; ++it) {
            int kq = tid + it * 256;
            if (kq < NF) {
                int s = __brev(kq) >> 22;
                float2 v = FD[pd(s)];
                ob[kq * 17 + cl] = pkh2(v.x, v.y);
            }
        }
        __syncthreads();
        nzA[0] = nzB[0]; nzA[1] = nzB[1]; nzA[2] = nzB[2]; nzA[3] = nzB[3];
    }

    // E global write: full 64B lines (16 cells x 4B per bin)
    for (int idx = tid; idx < NF * 16; idx += 256) {
        int kq = idx >> 4, cl2 = idx & 15;
        Et[((size_t)b * NF + kq) * NCELLS + c0 + cl2] = ob[kq * 17 + cl2];
    }
    __syncthreads();

    // tf pass: stage 2 rows at a time, clip, pack bin-pairs, transpose
    for (int rr = 0; rr < 16; rr += 2) {
        for (int k2 = tid; k2 < NF; k2 += 256) {
            float va = clip01(tf[((size_t)b * NCELLS + c0 + rr) * NF + k2]);
            float vb = clip01(tf[((size_t)b * NCELLS + c0 + rr + 1) * NF + k2]);
            FD[pd(k2)] = make_float2(va, vb);
        }
        __syncthreads();
        for (int kp = tid; kp < NKP; kp += 256) {
            float2 lo2 = FD[pd(2 * kp)];
            float2 hi2 = (2 * kp + 1 < NF) ? FD[pd(2 * kp + 1)] : make_float2(0.f, 0.f);
            ob[kp * 17 + rr]     = pkh2(lo2.x, hi2.x);
            ob[kp * 17 + rr + 1] = pkh2(lo2.y, hi2.y);
        }
        __syncthreads();
    }
    for (int idx = tid; idx < NKP * 16; idx += 256) {
        int kp = idx >> 4, cl2 = idx & 15;
        TFt[((size_t)b * NKP + kp) * NCELLS + c0 + cl2] = ob[kp * 17 + cl2];
    }
}

// ---------------- P2 ----------------
// WG = one bin (513 WGs, 256 threads). Thread q owns z-column of (x,y)=q.
__global__ __launch_bounds__(256) void k_p2(
    const unsigned* __restrict__ Et, const unsigned* __restrict__ TFt,
    float2* __restrict__ ms)
{
    __shared__ float2 S[256 * 17];           // column exchange, stride 17 (pad)

    const int q = threadIdx.x;
    const int k = blockIdx.x;
    const int kp = k >> 1, sel = k & 1;
    const int x = q >> 4, y = q & 15;

    float2 SF[16];
    #pragma unroll
    for (int z = 0; z < 16; ++z) SF[z] = make_float2(0.f, 0.f);

    uint4 EB[2][4], TB[2][4];
    {
        const uint4* ep = (const uint4*)(Et + ((size_t)0 * NF + k) * NCELLS + (q << 4));
        const uint4* tp = (const uint4*)(TFt + ((size_t)0 * NKP + kp) * NCELLS + (q << 4));
        EB[0][0] = ep[0]; EB[0][1] = ep[1]; EB[0][2] = ep[2]; EB[0][3] = ep[3];
        TB[0][0] = tp[0]; TB[0][1] = tp[1]; TB[0][2] = tp[2]; TB[0][3] = tp[3];
    }

    #pragma unroll
    for (int b = 0; b < 16; ++b) {
        const int cur = b & 1, nxt = cur ^ 1;
        if (b + 1 < 16) {   // compile-time after unroll
            const uint4* ep = (const uint4*)(Et + ((size_t)(b + 1) * NF + k) * NCELLS + (q << 4));
            const uint4* tp = (const uint4*)(TFt + ((size_t)(b + 1) * NKP + kp) * NCELLS + (q << 4));
            EB[nxt][0] = ep[0]; EB[nxt][1] = ep[1]; EB[nxt][2] = ep[2]; EB[nxt][3] = ep[3];
            TB[nxt][0] = tp[0]; TB[nxt][1] = tp[1]; TB[nxt][2] = tp[2]; TB[nxt][3] = tp[3];
        }

        // T = tf * (SF + E)
        float2 T[16];
        #pragma unroll
        for (int z = 0; z < 16; ++z) {
            unsigned eu = cmp4(EB[cur][z >> 2], z & 3);
            unsigned tu = cmp4(TB[cur][z >> 2], z & 3);
            union { unsigned u; _Float16 h[2]; } ue, ut;
            ue.u = eu; ut.u = tu;
            float r = sel ? (float)ut.h[1] : (float)ut.h[0];
            T[z] = make_float2(r * (SF[z].x + (float)ue.h[0]),
                               r * (SF[z].y + (float)ue.h[1]));
        }
        if (q == MICQ) ms[b * NF + k] = T[8];

        // z-sum in registers
        float2 Z[16];
        #pragma unroll
        for (int z = 0; z < 16; ++z) {
            float zr = T[z].x, zi = T[z].y;
            if (z > 0)  { zr += T[z - 1].x; zi += T[z - 1].y; }
            if (z < 15) { zr += T[z + 1].x; zi += T[z + 1].y; }
            Z[z] = make_float2(zr, zi);
        }
        // y-sum via LDS
        #pragma unroll
        for (int z = 0; z < 16; ++z) S[q * 17 + z] = Z[z];
        __syncthreads();
        float2 Y[16];
        #pragma unroll
        for (int z = 0; z < 16; ++z) {
            float yr = Z[z].x, yi = Z[z].y;
            if (y > 0)  { float2 v = S[(q - 1) * 17 + z]; yr += v.x; yi += v.y; }
            if (y < 15) { float2 v = S[(q + 1) * 17 + z]; yr += v.x; yi += v.y; }
            Y[z] = make_float2(yr, yi);
        }
        __syncthreads();
        // x-sum via LDS
        #pragma unroll
        for (int z = 0; z < 16; ++z) S[q * 17 + z] = Y[z];
        __syncthreads();
        #pragma unroll
        for (int z = 0; z < 16; ++z) {
            float sr = Y[z].x, si = Y[z].y;
            if (x > 0)  { float2 v = S[(q - 16) * 17 + z]; sr += v.x; si += v.y; }
            if (x < 15) { float2 v = S[(q + 16) * 17 + z]; sr += v.x; si += v.y; }
            SF[z] = make_float2(sr, si);
        }
        __syncthreads();
    }
}

// ---------------- P3 ----------------
// One WG per block: rebuild full spectrum (conj symmetry), inverse DIT, write mic.
__global__ __launch_bounds__(256) void k_p3(
    const float2* __restrict__ ms, float* __restrict__ out)
{
    __shared__ float2 FD[1056];
    const int b = blockIdx.x, tid = threadIdx.x;

    for (int j = tid; j < NFFT; j += 256) {
        int jj = (j <= 512) ? j : 1024 - j;
        float2 v = ms[b * NF + jj];
        if (j > 512) v.y = -v.y;
        FD[pd(__brev(j) >> 22)] = v;
    }
    __syncthreads();

    for (int lg = 0; lg <= 9; ++lg) {
        const int len = 1 << lg;
        for (int pr = tid; pr < 512; pr += 256) {
            const int jj = pr & (len - 1);
            const int i0 = ((pr >> lg) << (lg + 1)) + jj;
            const int i1 = i0 + len;
            const int iw = jj << (9 - lg);
            float sn, cs;
            __sincosf(-PI2 * (1.0f / 1024.0f) * (float)iw, &sn, &cs);
            float2 a = FD[pd(i0)], bb = FD[pd(i1)];
            float tr = bb.x * cs + bb.y * sn;    // b * conj(W)
            float ti = bb.y * cs - bb.x * sn;
            FD[pd(i0)] = make_float2(a.x + tr, a.y + ti);
            FD[pd(i1)] = make_float2(a.x - tr, a.y - ti);
        }
        __syncthreads();
    }
    for (int t = tid; t < NFFT; t += 256)
        out[b * NFFT + t] = FD[pd(t)].x * (1.0f / 1024.0f);
}

extern "C" void kernel_launch(void* const* d_in, const int* in_sizes, int n_in,
                              void* d_out, int out_size, void* d_ws, size_t ws_size,
                              hipStream_t stream)
{
    const float* tf    = (const float*)d_in[1];
    const float* imp   = (const float*)d_in[2];
    const float* noise = (const float*)d_in[3];
    float* out = (float*)d_out;

    unsigned* Et  = (unsigned*)d_ws;                       // 16*513*4096 u32 (fp16x2)
    unsigned* TFt = Et + (size_t)16 * NF * NCELLS;         // 16*257*4096 u32 (fp16x2)
    float2*   ms  = (float2*)(TFt + (size_t)16 * NKP * NCELLS);  // 16*513 c64

    k_p1<<<4096, 256, 0, stream>>>(tf, imp, noise, Et, TFt);
    k_p2<<<NF, 256, 0, stream>>>(Et, TFt, ms);
    k_p3<<<16, 256, 0, stream>>>(ms, out);
}

// Round 4
// 363.267 us; speedup vs baseline: 2.9516x; 1.1901x over previous
//
#include <hip/hip_runtime.h>

// Frequency-domain room sim, 3-kernel phase split.
//   SF = DFT(sound_field) per cell (unnormalized); per block b:
//     T = clip(res,0,1) * (SF + DFT(env_b));  mic_b = IDFT(T[mic])/1024;
//     SF = box3x3x3(T)   (pointwise per bin -> recursion independent per bin)
// P1: all env FFTs (2 real cells packed per complex FFT) + transpose to
//     (b,bin,cell) fp16; tf clip+pack likewise. 4 cells per WG, ~18KB LDS.
// P2: one WG per bin (513); 16-block recursion fully in registers.
// P3: 16 inverse FFTs of the mic spectra.

#define NFFT   1024
#define NF     513
#define NKP    257
#define NCELLS 4096
#define MICQ   136      // x*16+y = 8*16+8
#define PI2    6.28318530717958647692f

// FFT LDS skew: conflict-checked <=3-way for all pass strides + bitrev gather
__device__ __forceinline__ int IDX(int i) { return i + (i >> 5) + ((i >> 6) << 3); }
// transpose-buffer swizzle: bijective, 2-way on both write and read phases
__device__ __forceinline__ int OBX(int kq, int cl) { return (kq << 2) | ((cl + (kq >> 3)) & 3); }

__device__ __forceinline__ float clip01(float v) { return fminf(fmaxf(v, 0.0f), 1.0f); }
__device__ __forceinline__ unsigned pkh2(float a, float b) {
    union { _Float16 h[2]; unsigned u; } z;
    z.h[0] = (_Float16)a; z.h[1] = (_Float16)b;
    return z.u;
}
__device__ __forceinline__ unsigned cmp4(const uint4& v, int c) {
    return c == 0 ? v.x : c == 1 ? v.y : c == 2 ? v.z : v.w;
}
__device__ __forceinline__ float f4c(const float4& v, int c) {
    return c == 0 ? v.x : c == 1 ? v.y : c == 2 ? v.z : v.w;
}

// ---------------- P1 ----------------
// WG = (block b, 4 cells). 256 threads. Grid 16*1024.
__global__ __launch_bounds__(256) void k_p1(
    const float* __restrict__ tf, const float* __restrict__ imp,
    const float* __restrict__ noise, unsigned* __restrict__ Et,
    unsigned* __restrict__ TFt)
{
    __shared__ float re[1184], im[1184];
    __shared__ unsigned ob[2080];          // 513*4 swizzled transpose buffer

    const int tid = threadIdx.x;
    const int b   = blockIdx.x >> 10;
    const int c0  = (blockIdx.x & 1023) << 2;

    // per-thread twiddles for the 5 fused (2x radix-2) DIF passes
    float2 tu0[5], tu1[5], tl[5];
    #pragma unroll
    for (int p = 0; p < 5; ++p) {
        const int lgU = 9 - 2 * p, lgL = lgU - 1, LL = 1 << lgL;
        const int j = tid & (LL - 1);
        const int iu0 = j << (9 - lgU), iu1 = (j + LL) << (9 - lgU), il = j << (9 - lgL);
        float s, c;
        __sincosf(-PI2 * (1.0f / 1024.0f) * (float)iu0, &s, &c); tu0[p] = make_float2(c, s);
        __sincosf(-PI2 * (1.0f / 1024.0f) * (float)iu1, &s, &c); tu1[p] = make_float2(c, s);
        __sincosf(-PI2 * (1.0f / 1024.0f) * (float)il,  &s, &c); tl[p]  = make_float2(c, s);
    }

    // interp coefficients for this thread's 4 samples (n = 4*tid + c)
    int lo_[4], hi_[4]; float w_[4];
    #pragma unroll
    for (int c = 0; c < 4; ++c) {
        int n = 4 * tid + c;
        float coord = (n + 0.5f) * (16.0f / 1024.0f) - 0.5f;
        coord = fminf(fmaxf(coord, 0.0f), 15.0f);
        int lo = (int)coord;
        lo_[c] = lo;
        hi_[c] = lo + 1 > 15 ? 15 : lo + 1;
        w_[c]  = coord - (float)lo;
    }

    #pragma unroll
    for (int pc = 0; pc < 2; ++pc) {
        const int cA = c0 + 2 * pc;
        const float* ipA = imp + ((size_t)b * NCELLS + cA) * 16;
        const float* ipB = ipA + 16;
        const float4 nA = *(const float4*)(noise + ((size_t)b * NCELLS + cA) * NFFT + 4 * tid);
        const float4 nB = *(const float4*)(noise + ((size_t)b * NCELLS + cA + 1) * NFFT + 4 * tid);

        if (pc) __syncthreads();          // previous extract must finish reading re/im

        // s[n] = envA[n] + i*envB[n]
        #pragma unroll
        for (int c = 0; c < 4; ++c) {
            int n = 4 * tid + c;
            float eA = clip01(ipA[lo_[c]] * (1.0f - w_[c]) + ipA[hi_[c]] * w_[c]) * f4c(nA, c);
            float eB = clip01(ipB[lo_[c]] * (1.0f - w_[c]) + ipB[hi_[c]] * w_[c]) * f4c(nB, c);
            re[IDX(n)] = eA;
            im[IDX(n)] = eB;
        }
        __syncthreads();

        // forward FFT: 10 radix-2 DIF stages, fused 2/pass (thread owns a
        // closed 4-point group per pass -> one sync per pass)
        #pragma unroll
        for (int p = 0; p < 5; ++p) {
            const int lgU = 9 - 2 * p, lgL = lgU - 1, LL = 1 << lgL;
            const int j = tid & (LL - 1), g = tid >> lgL;
            const int base = (g << (lgL + 2)) + j;
            const int q0 = IDX(base), q1 = IDX(base + LL);
            const int q2 = IDX(base + 2 * LL), q3 = IDX(base + 3 * LL);
            float a0r = re[q0], a0i = im[q0];
            float a1r = re[q1], a1i = im[q1];
            float a2r = re[q2], a2i = im[q2];
            float a3r = re[q3], a3i = im[q3];
            float2 w0 = tu0[p], w1 = tu1[p], wl = tl[p];
            float u0r = a0r + a2r, u0i = a0i + a2i;
            float d0r = a0r - a2r, d0i = a0i - a2i;
            float u2r = d0r * w0.x - d0i * w0.y, u2i = d0r * w0.y + d0i * w0.x;
            float u1r = a1r + a3r, u1i = a1i + a3i;
            float d1r = a1r - a3r, d1i = a1i - a3i;
            float u3r = d1r * w1.x - d1i * w1.y, u3i = d1r * w1.y + d1i * w1.x;
            float e0r = u0r - u1r, e0i = u0i - u1i;
            float e1r = u2r - u3r, e1i = u2i - u3i;
            re[q0] = u0r + u1r;               im[q0] = u0i + u1i;
            re[q1] = e0r * wl.x - e0i * wl.y; im[q1] = e0r * wl.y + e0i * wl.x;
            re[q2] = u2r + u3r;               im[q2] = u2i + u3i;
            re[q3] = e1r * wl.x - e1i * wl.y; im[q3] = e1r * wl.y + e1i * wl.x;
            __syncthreads();
        }

        // split packed spectrum: Ea = (F(k)+conj(F(-k)))/2, Eb = (F(k)-conj(F(-k)))/2i
        #pragma unroll
        for (int it = 0; it < 3; ++it) {
            int kq = tid + it * 256;
            if (kq < NF) {
                int s  = IDX(__brev(kq) >> 22);
                int s2 = IDX(__brev((1024 - kq) & 1023) >> 22);
                float fr = re[s],  fi = im[s];
                float gr = re[s2], gi = im[s2];
                float ear = 0.5f * (fr + gr), eai = 0.5f * (fi - gi);
                float ebr = 0.5f * (fi + gi), ebi = 0.5f * (gr - fr);
                ob[OBX(kq, 2 * pc)]     = pkh2(ear, eai);
                ob[OBX(kq, 2 * pc + 1)] = pkh2(ebr, ebi);
            }
        }
    }
    __syncthreads();

    // Et write-out: 16B sectors per (b,kq) line, merged in L2 within this WG
    for (int idx = tid; idx < NF * 4; idx += 256) {
        int kq = idx >> 2, cl = idx & 3;
        Et[((size_t)b * NF + kq) * NCELLS + c0 + cl] = ob[OBX(kq, cl)];
    }
    __syncthreads();

    // tf: clip + pack bin pairs (2kp, 2kp+1) per cell
    #pragma unroll
    for (int cl = 0; cl < 4; ++cl) {
        const float* row = tf + ((size_t)b * NCELLS + c0 + cl) * NF;
        for (int kp = tid; kp < NKP; kp += 256) {
            float f0 = clip01(row[2 * kp]);
            float f1 = (kp < 256) ? clip01(row[2 * kp + 1]) : 0.0f;
            ob[OBX(kp, cl)] = pkh2(f0, f1);
        }
    }
    __syncthreads();
    for (int idx = tid; idx < NKP * 4; idx += 256) {
        int kp = idx >> 2, cl = idx & 3;
        TFt[((size_t)b * NKP + kp) * NCELLS + c0 + cl] = ob[OBX(kp, cl)];
    }
}

// ---------------- P2 ----------------
// WG = one bin (513 WGs, 256 threads). Thread q owns z-column of (x,y)=q.
__global__ __launch_bounds__(256) void k_p2(
    const unsigned* __restrict__ Et, const unsigned* __restrict__ TFt,
    float2* __restrict__ ms)
{
    __shared__ float2 S[256 * 17];

    const int q = threadIdx.x;
    const int k = blockIdx.x;
    const int kp = k >> 1, sel = k & 1;
    const int x = q >> 4, y = q & 15;

    float2 SF[16];
    #pragma unroll
    for (int z = 0; z < 16; ++z) SF[z] = make_float2(0.f, 0.f);

    uint4 EB[2][4], TB[2][4];
    {
        const uint4* ep = (const uint4*)(Et + (size_t)k * NCELLS + (q << 4));
        const uint4* tp = (const uint4*)(TFt + (size_t)kp * NCELLS + (q << 4));
        EB[0][0] = ep[0]; EB[0][1] = ep[1]; EB[0][2] = ep[2]; EB[0][3] = ep[3];
        TB[0][0] = tp[0]; TB[0][1] = tp[1]; TB[0][2] = tp[2]; TB[0][3] = tp[3];
    }

    #pragma unroll
    for (int b = 0; b < 16; ++b) {
        const int cur = b & 1, nxt = cur ^ 1;
        if (b + 1 < 16) {
            const uint4* ep = (const uint4*)(Et + ((size_t)(b + 1) * NF + k) * NCELLS + (q << 4));
            const uint4* tp = (const uint4*)(TFt + ((size_t)(b + 1) * NKP + kp) * NCELLS + (q << 4));
            EB[nxt][0] = ep[0]; EB[nxt][1] = ep[1]; EB[nxt][2] = ep[2]; EB[nxt][3] = ep[3];
            TB[nxt][0] = tp[0]; TB[nxt][1] = tp[1]; TB[nxt][2] = tp[2]; TB[nxt][3] = tp[3];
        }

        float2 T[16];
        #pragma unroll
        for (int z = 0; z < 16; ++z) {
            unsigned eu = cmp4(EB[cur][z >> 2], z & 3);
            unsigned tu = cmp4(TB[cur][z >> 2], z & 3);
            union { unsigned u; _Float16 h[2]; } ue, ut;
            ue.u = eu; ut.u = tu;
            float r = sel ? (float)ut.h[1] : (float)ut.h[0];
            T[z] = make_float2(r * (SF[z].x + (float)ue.h[0]),
                               r * (SF[z].y + (float)ue.h[1]));
        }
        if (q == MICQ) ms[b * NF + k] = T[8];

        float2 Z[16];
        #pragma unroll
        for (int z = 0; z < 16; ++z) {
            float zr = T[z].x, zi = T[z].y;
            if (z > 0)  { zr += T[z - 1].x; zi += T[z - 1].y; }
            if (z < 15) { zr += T[z + 1].x; zi += T[z + 1].y; }
            Z[z] = make_float2(zr, zi);
        }
        #pragma unroll
        for (int z = 0; z < 16; ++z) S[q * 17 + z] = Z[z];
        __syncthreads();
        float2 Y[16];
        #pragma unroll
        for (int z = 0; z < 16; ++z) {
            float yr = Z[z].x, yi = Z[z].y;
            if (y > 0)  { float2 v = S[(q - 1) * 17 + z]; yr += v.x; yi += v.y; }
            if (y < 15) { float2 v = S[(q + 1) * 17 + z]; yr += v.x; yi += v.y; }
            Y[z] = make_float2(yr, yi);
        }
        __syncthreads();
        #pragma unroll
        for (int z = 0; z < 16; ++z) S[q * 17 + z] = Y[z];
        __syncthreads();
        #pragma unroll
        for (int z = 0; z < 16; ++z) {
            float sr = Y[z].x, si = Y[z].y;
            if (x > 0)  { float2 v = S[(q - 16) * 17 + z]; sr += v.x; si += v.y; }
            if (x < 15) { float2 v = S[(q + 16) * 17 + z]; sr += v.x; si += v.y; }
            SF[z] = make_float2(sr, si);
        }
        __syncthreads();
    }
}

// ---------------- P3 ----------------
__device__ __forceinline__ int pd(int i) { return i + (i >> 5); }

__global__ __launch_bounds__(256) void k_p3(
    const float2* __restrict__ ms, float* __restrict__ out)
{
    __shared__ float2 FD[1056];
    const int b = blockIdx.x, tid = threadIdx.x;

    for (int j = tid; j < NFFT; j += 256) {
        int jj = (j <= 512) ? j : 1024 - j;
        float2 v = ms[b * NF + jj];
        if (j > 512) v.y = -v.y;
        FD[pd(__brev(j) >> 22)] = v;
    }
    __syncthreads();

    for (int lg = 0; lg <= 9; ++lg) {
        const int len = 1 << lg;
        for (int pr = tid; pr < 512; pr += 256) {
            const int jj = pr & (len - 1);
            const int i0 = ((pr >> lg) << (lg + 1)) + jj;
            const int i1 = i0 + len;
            const int iw = jj << (9 - lg);
            float sn, cs;
            __sincosf(-PI2 * (1.0f / 1024.0f) * (float)iw, &sn, &cs);
            float2 a = FD[pd(i0)], bb = FD[pd(i1)];
            float tr = bb.x * cs + bb.y * sn;
            float ti = bb.y * cs - bb.x * sn;
            FD[pd(i0)] = make_float2(a.x + tr, a.y + ti);
            FD[pd(i1)] = make_float2(a.x - tr, a.y - ti);
        }
        __syncthreads();
    }
    for (int t = tid; t < NFFT; t += 256)
        out[b * NFFT + t] = FD[pd(t)].x * (1.0f / 1024.0f);
}

extern "C" void kernel_launch(void* const* d_in, const int* in_sizes, int n_in,
                              void* d_out, int out_size, void* d_ws, size_t ws_size,
                              hipStream_t stream)
{
    const float* tf    = (const float*)d_in[1];
    const float* imp   = (const float*)d_in[2];
    const float* noise = (const float*)d_in[3];
    float* out = (float*)d_out;

    unsigned* Et  = (unsigned*)d_ws;                             // 16*513*4096 u32
    unsigned* TFt = Et + (size_t)16 * NF * NCELLS;               // 16*257*4096 u32
    float2*   ms  = (float2*)(TFt + (size_t)16 * NKP * NCELLS);  // 16*513 c64

    k_p1<<<16 * 1024, 256, 0, stream>>>(tf, imp, noise, Et, TFt);
    k_p2<<<NF, 256, 0, stream>>>(Et, TFt, ms);
    k_p3<<<16, 256, 0, stream>>>(ms, out);
}